// Round 1
// baseline (999.166 us; speedup 1.0000x reference)
//
#include <hip/hip_runtime.h>
#include <stdint.h>

// Problem constants (fixed by the reference)
#define IN_F   4096
#define OUT_F  11008
#define QCOLS  (OUT_F / 8)   // 1376 packed int32 columns
#define NGRP   32            // IN_F / 128 quant groups
#define M_TOT  4096          // 2 * 2048

// Tiling
#define BM 128
#define BN 128
#define BK 32
#define LDA 40               // padded LDS stride (bf16 elems): 80 B rows -> 16B ops tile banks cleanly
#define LDB 40

typedef __attribute__((ext_vector_type(8))) short short8;
typedef __attribute__((ext_vector_type(4))) float floatx4;

// fp32 -> bf16 round-to-nearest-even
__device__ __forceinline__ short f2bf(float f) {
    union { float f; uint32_t u; } v; v.f = f;
    uint32_t u = v.u;
    u += 0x7FFFu + ((u >> 16) & 1u);
    return (short)(u >> 16);
}

__global__ __launch_bounds__(256, 2)
void wql_kernel(const float* __restrict__ A,
                const int*   __restrict__ qw,
                const int*   __restrict__ qz,
                const float* __restrict__ scl,
                float*       __restrict__ out)
{
    __shared__ short As[BM * LDA];
    __shared__ short Bs[BN * LDB];

    const int tid = threadIdx.x;
    const int m0  = blockIdx.y * BM;
    const int n0  = blockIdx.x * BN;

    // ---- A staging role: thread owns (row = tid/2, 16 k starting at (tid&1)*16)
    const int a_row  = tid >> 1;
    const int a_kseg = (tid & 1) << 4;
    const float* a_base = A + (size_t)(m0 + a_row) * IN_F + a_kseg;
    short* a_wr = &As[a_row * LDA + a_kseg];

    // ---- B staging role: thread owns one output column n, 16 consecutive k
    const int b_n     = tid & 127;          // local n in [0,128)
    const int b_khalf = (tid >> 7) << 4;    // 0 or 16
    const int c_glob  = (n0 >> 3) + (b_n >> 3);  // packed column
    const int shift   = (b_n & 7) << 2;          // nibble position (fixed per thread)
    short* b_wr = &Bs[b_n * LDB + b_khalf];

    // ---- MFMA roles
    const int lane = tid & 63;
    const int wm   = ((tid >> 7) & 1) << 6;      // wave row  (waves 0,1 -> 0 ; 2,3 -> 64)
    const int wn   = ((tid >> 6) & 1) << 6;      // wave col
    const int lrow = lane & 15;
    const int quad = lane >> 4;

    const short* a_rd = &As[(wm + lrow) * LDA + quad * 8];
    const short* b_rd = &Bs[(wn + lrow) * LDB + quad * 8];

    floatx4 acc[4][4];
    #pragma unroll
    for (int i = 0; i < 4; ++i)
        #pragma unroll
        for (int j = 0; j < 4; ++j)
            acc[i][j] = (floatx4)0.f;

    for (int g = 0; g < NGRP; ++g) {
        // group-invariant dequant constants for this thread's column
        const uint32_t z  = (uint32_t)qz[g * QCOLS + c_glob];
        const float    sc = scl[g * OUT_F + n0 + b_n];
        const float    zo = -(float)((z >> shift) & 15u) * sc;

        #pragma unroll 1
        for (int t4 = 0; t4 < 4; ++t4) {
            const int k0 = (g << 7) + (t4 << 5);

            // ---- global loads (before barrier so they fly during the wait)
            const float4* ap = (const float4*)(a_base + k0);
            float4 av0 = ap[0], av1 = ap[1], av2 = ap[2], av3 = ap[3];

            const int* qp = qw + (size_t)(k0 + b_khalf) * QCOLS + c_glob;
            uint32_t qv[16];
            #pragma unroll
            for (int kk = 0; kk < 16; ++kk) qv[kk] = (uint32_t)qp[kk * QCOLS];

            __syncthreads();   // previous iteration's compute done reading LDS

            // ---- A: fp32 -> bf16, two 16B LDS writes
            short8 aw0, aw1;
            aw0[0]=f2bf(av0.x); aw0[1]=f2bf(av0.y); aw0[2]=f2bf(av0.z); aw0[3]=f2bf(av0.w);
            aw0[4]=f2bf(av1.x); aw0[5]=f2bf(av1.y); aw0[6]=f2bf(av1.z); aw0[7]=f2bf(av1.w);
            aw1[0]=f2bf(av2.x); aw1[1]=f2bf(av2.y); aw1[2]=f2bf(av2.z); aw1[3]=f2bf(av2.w);
            aw1[4]=f2bf(av3.x); aw1[5]=f2bf(av3.y); aw1[6]=f2bf(av3.z); aw1[7]=f2bf(av3.w);
            *(short8*)a_wr       = aw0;
            *(short8*)(a_wr + 8) = aw1;

            // ---- B: dequant 16 k-consecutive values of this thread's column
            short8 bw0, bw1;
            #pragma unroll
            for (int kk = 0; kk < 8; ++kk)
                bw0[kk] = f2bf(fmaf((float)((qv[kk] >> shift) & 15u), sc, zo));
            #pragma unroll
            for (int kk = 0; kk < 8; ++kk)
                bw1[kk] = f2bf(fmaf((float)((qv[8 + kk] >> shift) & 15u), sc, zo));
            *(short8*)b_wr       = bw0;
            *(short8*)(b_wr + 8) = bw1;

            __syncthreads();   // tiles visible

            // ---- 4x4 MFMA
            short8 af[4], bf[4];
            #pragma unroll
            for (int mt = 0; mt < 4; ++mt)
                af[mt] = *(const short8*)(a_rd + mt * 16 * LDA);
            #pragma unroll
            for (int nt = 0; nt < 4; ++nt)
                bf[nt] = *(const short8*)(b_rd + nt * 16 * LDB);

            #pragma unroll
            for (int mt = 0; mt < 4; ++mt)
                #pragma unroll
                for (int nt = 0; nt < 4; ++nt)
                    acc[mt][nt] = __builtin_amdgcn_mfma_f32_16x16x32_bf16(
                        af[mt], bf[nt], acc[mt][nt], 0, 0, 0);
        }
    }

    // ---- epilogue: C/D layout col = lane&15, row = quad*4 + reg
    #pragma unroll
    for (int mt = 0; mt < 4; ++mt) {
        #pragma unroll
        for (int nt = 0; nt < 4; ++nt) {
            const int col = n0 + wn + nt * 16 + lrow;
            float* op = out + (size_t)(m0 + wm + mt * 16 + quad * 4) * OUT_F + col;
            #pragma unroll
            for (int r = 0; r < 4; ++r)
                op[(size_t)r * OUT_F] = acc[mt][nt][r];
        }
    }
}

extern "C" void kernel_launch(void* const* d_in, const int* in_sizes, int n_in,
                              void* d_out, int out_size, void* d_ws, size_t ws_size,
                              hipStream_t stream) {
    const float* input   = (const float*)d_in[0];
    const int*   qweight = (const int*)d_in[1];
    const int*   qzeros  = (const int*)d_in[2];
    const float* scales  = (const float*)d_in[3];
    float*       out     = (float*)d_out;

    dim3 grid(OUT_F / BN, M_TOT / BM);   // (86, 32)
    wql_kernel<<<grid, 256, 0, stream>>>(input, qweight, qzeros, scales, out);
}

// Round 2
// 728.083 us; speedup vs baseline: 1.3723x; 1.3723x over previous
//
#include <hip/hip_runtime.h>
#include <stdint.h>

// Problem constants
#define IN_F   4096
#define OUT_F  11008
#define QCOLS  (OUT_F / 8)   // 1376
#define NGRP   32
#define M_TOT  4096

typedef __attribute__((ext_vector_type(8))) short short8;
typedef __attribute__((ext_vector_type(4))) float floatx4;

// fp32 -> bf16 round-to-nearest-even
__device__ __forceinline__ short f2bf(float f) {
    union { float f; uint32_t u; } v; v.f = f;
    uint32_t u = v.u;
    u += 0x7FFFu + ((u >> 16) & 1u);
    return (short)(u >> 16);
}

// ---------------------------------------------------------------------------
// Kernel 1: dequant qweight (4-bit, group=128) -> bf16 W^T[n][k] in workspace
// thread = (c packed-col, kblk of 32 k). 176,128 threads total.
// ---------------------------------------------------------------------------
__global__ __launch_bounds__(256)
void dequant_kernel(const int* __restrict__ qw, const int* __restrict__ qz,
                    const float* __restrict__ scl, short* __restrict__ wt)
{
    const int t    = blockIdx.x * 256 + threadIdx.x;
    const int c    = t % QCOLS;
    const int kblk = t / QCOLS;          // 0..127
    const int k0   = kblk << 5;
    const int g    = kblk >> 2;          // quant group (32 k-block fits in one group)

    uint32_t q[32];
    const int* qp = qw + (size_t)k0 * QCOLS + c;
    #pragma unroll
    for (int kk = 0; kk < 32; ++kk) q[kk] = (uint32_t)qp[(size_t)kk * QCOLS];

    const uint32_t z = (uint32_t)qz[g * QCOLS + c];
    const float* sp = scl + (size_t)g * OUT_F + c * 8;
    const float4 s0 = *(const float4*)sp;
    const float4 s1 = *(const float4*)(sp + 4);
    const float sc8[8] = {s0.x, s0.y, s0.z, s0.w, s1.x, s1.y, s1.z, s1.w};

    #pragma unroll
    for (int j = 0; j < 8; ++j) {
        const int sh = j << 2;
        const float sc = sc8[j];
        const float zo = -(float)((z >> sh) & 15u) * sc;
        short8 o0, o1, o2, o3;
        #pragma unroll
        for (int kk = 0; kk < 8; ++kk) {
            o0[kk] = f2bf(fmaf((float)((q[kk]      >> sh) & 15u), sc, zo));
            o1[kk] = f2bf(fmaf((float)((q[kk + 8]  >> sh) & 15u), sc, zo));
            o2[kk] = f2bf(fmaf((float)((q[kk + 16] >> sh) & 15u), sc, zo));
            o3[kk] = f2bf(fmaf((float)((q[kk + 24] >> sh) & 15u), sc, zo));
        }
        short* dst = wt + (size_t)(c * 8 + j) * IN_F + k0;
        *(short8*)(dst)      = o0;
        *(short8*)(dst + 8)  = o1;
        *(short8*)(dst + 16) = o2;
        *(short8*)(dst + 24) = o3;
    }
}

// ---------------------------------------------------------------------------
// Kernel 2: cast A fp32 -> bf16 (row-major [m][k]) in workspace
// ---------------------------------------------------------------------------
__global__ __launch_bounds__(256)
void cast_kernel(const float* __restrict__ A, short* __restrict__ Ab)
{
    const size_t i = ((size_t)blockIdx.x * 256 + threadIdx.x) * 8;
    const float4 a0 = *(const float4*)(A + i);
    const float4 a1 = *(const float4*)(A + i + 4);
    short8 o;
    o[0] = f2bf(a0.x); o[1] = f2bf(a0.y); o[2] = f2bf(a0.z); o[3] = f2bf(a0.w);
    o[4] = f2bf(a1.x); o[5] = f2bf(a1.y); o[6] = f2bf(a1.z); o[7] = f2bf(a1.w);
    *(short8*)(Ab + i) = o;
}

// ---------------------------------------------------------------------------
// Kernel 3: bf16 GEMM, m97-style. 128x128 tile, BK=64, global_load_lds w=16,
// XOR-swizzled LDS (16B segs) to avoid b128 bank conflicts at 128B row stride.
// ---------------------------------------------------------------------------
#define GBK 64

__global__ __launch_bounds__(256, 3)
void gemm_kernel(const short* __restrict__ Ab, const short* __restrict__ Bt,
                 float* __restrict__ out)
{
    __shared__ short As[128 * GBK];   // 16 KB, unpadded (global_load_lds req.)
    __shared__ short Bs[128 * GBK];   // 16 KB

    const int tid  = threadIdx.x;
    const int lane = tid & 63;
    const int w    = tid >> 6;
    const int m0   = blockIdx.y * 128;
    const int n0   = blockIdx.x * 128;

    // ---- staging: wave w owns slots w*4..w*4+3; slot = 8 rows x 128 B.
    // lane l: row = slot*8 + l/8 ; global k-seg = (l%8) ^ (l/8)  [XOR swizzle]
    const int srow = lane >> 3;                 // 0..7 (== row & 7)
    const int kseg = (lane & 7) ^ srow;
    const short* agp[4];
    const short* bgp[4];
    short* alp[4];
    short* blp[4];
    #pragma unroll
    for (int s = 0; s < 4; ++s) {
        const int slot = w * 4 + s;
        const int row  = slot * 8 + srow;
        agp[s] = Ab + (size_t)(m0 + row) * IN_F + kseg * 8;
        bgp[s] = Bt + (size_t)(n0 + row) * IN_F + kseg * 8;
        alp[s] = As + slot * 512;   // HW appends lane*16B
        blp[s] = Bs + slot * 512;
    }

    // ---- MFMA fragment roles
    const int lrow = lane & 15;
    const int quad = lane >> 4;
    const int wm   = ((w >> 1) & 1) << 6;
    const int wn   = (w & 1) << 6;

    // fragment LDS offsets (shorts), ks=0; ks=1 is ^32 (flips seg bit 2)
    int aoff[4], boff[4];
    #pragma unroll
    for (int i = 0; i < 4; ++i) {
        const int swz = (quad ^ (lrow & 7)) * 8;
        aoff[i] = (wm + i * 16 + lrow) * GBK + swz;
        boff[i] = (wn + i * 16 + lrow) * GBK + swz;
    }

    floatx4 acc[4][4];
    #pragma unroll
    for (int i = 0; i < 4; ++i)
        #pragma unroll
        for (int j = 0; j < 4; ++j)
            acc[i][j] = (floatx4)0.f;

    for (int it = 0; it < IN_F / GBK; ++it) {
        __syncthreads();   // previous tile fully consumed
        #pragma unroll
        for (int s = 0; s < 4; ++s) {
            __builtin_amdgcn_global_load_lds(
                (const __attribute__((address_space(1))) void*)agp[s],
                (__attribute__((address_space(3))) void*)alp[s], 16, 0, 0);
            __builtin_amdgcn_global_load_lds(
                (const __attribute__((address_space(1))) void*)bgp[s],
                (__attribute__((address_space(3))) void*)blp[s], 16, 0, 0);
            agp[s] += GBK;
            bgp[s] += GBK;
        }
        __syncthreads();   // vmcnt(0) drained before barrier -> tiles ready

        #pragma unroll
        for (int kx = 0; kx < 64; kx += 32) {   // two k=32 chunks, seg-xor kx
            short8 af[4], bf[4];
            #pragma unroll
            for (int mt = 0; mt < 4; ++mt)
                af[mt] = *(const short8*)(As + (aoff[mt] ^ kx));
            #pragma unroll
            for (int nt = 0; nt < 4; ++nt)
                bf[nt] = *(const short8*)(Bs + (boff[nt] ^ kx));
            #pragma unroll
            for (int mt = 0; mt < 4; ++mt)
                #pragma unroll
                for (int nt = 0; nt < 4; ++nt)
                    acc[mt][nt] = __builtin_amdgcn_mfma_f32_16x16x32_bf16(
                        af[mt], bf[nt], acc[mt][nt], 0, 0, 0);
        }
    }

    // ---- epilogue: C/D layout col = lane&15, row = quad*4 + reg
    #pragma unroll
    for (int mt = 0; mt < 4; ++mt) {
        #pragma unroll
        for (int nt = 0; nt < 4; ++nt) {
            const int col = n0 + wn + nt * 16 + lrow;
            float* op = out + (size_t)(m0 + wm + mt * 16 + quad * 4) * OUT_F + col;
            #pragma unroll
            for (int r = 0; r < 4; ++r)
                op[(size_t)r * OUT_F] = acc[mt][nt][r];
        }
    }
}

// ---------------------------------------------------------------------------
// Fallback: round-1 fused kernel (used only if workspace is too small)
// ---------------------------------------------------------------------------
#define BM 128
#define BN 128
#define LDA 40
#define LDB 40

__global__ __launch_bounds__(256, 2)
void wql_kernel(const float* __restrict__ A,
                const int*   __restrict__ qw,
                const int*   __restrict__ qz,
                const float* __restrict__ scl,
                float*       __restrict__ out)
{
    __shared__ short As[BM * LDA];
    __shared__ short Bs[BN * LDB];

    const int tid = threadIdx.x;
    const int m0  = blockIdx.y * BM;
    const int n0  = blockIdx.x * BN;

    const int a_row  = tid >> 1;
    const int a_kseg = (tid & 1) << 4;
    const float* a_base = A + (size_t)(m0 + a_row) * IN_F + a_kseg;
    short* a_wr = &As[a_row * LDA + a_kseg];

    const int b_n     = tid & 127;
    const int b_khalf = (tid >> 7) << 4;
    const int c_glob  = (n0 >> 3) + (b_n >> 3);
    const int shift   = (b_n & 7) << 2;
    short* b_wr = &Bs[b_n * LDB + b_khalf];

    const int lane = tid & 63;
    const int wm   = ((tid >> 7) & 1) << 6;
    const int wn   = ((tid >> 6) & 1) << 6;
    const int lrow = lane & 15;
    const int quad = lane >> 4;

    const short* a_rd = &As[(wm + lrow) * LDA + quad * 8];
    const short* b_rd = &Bs[(wn + lrow) * LDB + quad * 8];

    floatx4 acc[4][4];
    #pragma unroll
    for (int i = 0; i < 4; ++i)
        #pragma unroll
        for (int j = 0; j < 4; ++j)
            acc[i][j] = (floatx4)0.f;

    for (int g = 0; g < NGRP; ++g) {
        const uint32_t z  = (uint32_t)qz[g * QCOLS + c_glob];
        const float    sc = scl[g * OUT_F + n0 + b_n];
        const float    zo = -(float)((z >> shift) & 15u) * sc;

        #pragma unroll 1
        for (int t4 = 0; t4 < 4; ++t4) {
            const int k0 = (g << 7) + (t4 << 5);
            const float4* ap = (const float4*)(a_base + k0);
            float4 av0 = ap[0], av1 = ap[1], av2 = ap[2], av3 = ap[3];

            const int* qp = qw + (size_t)(k0 + b_khalf) * QCOLS + c_glob;
            uint32_t qv[16];
            #pragma unroll
            for (int kk = 0; kk < 16; ++kk) qv[kk] = (uint32_t)qp[kk * QCOLS];

            __syncthreads();

            short8 aw0, aw1;
            aw0[0]=f2bf(av0.x); aw0[1]=f2bf(av0.y); aw0[2]=f2bf(av0.z); aw0[3]=f2bf(av0.w);
            aw0[4]=f2bf(av1.x); aw0[5]=f2bf(av1.y); aw0[6]=f2bf(av1.z); aw0[7]=f2bf(av1.w);
            aw1[0]=f2bf(av2.x); aw1[1]=f2bf(av2.y); aw1[2]=f2bf(av2.z); aw1[3]=f2bf(av2.w);
            aw1[4]=f2bf(av3.x); aw1[5]=f2bf(av3.y); aw1[6]=f2bf(av3.z); aw1[7]=f2bf(av3.w);
            *(short8*)a_wr       = aw0;
            *(short8*)(a_wr + 8) = aw1;

            short8 bw0, bw1;
            #pragma unroll
            for (int kk = 0; kk < 8; ++kk)
                bw0[kk] = f2bf(fmaf((float)((qv[kk] >> shift) & 15u), sc, zo));
            #pragma unroll
            for (int kk = 0; kk < 8; ++kk)
                bw1[kk] = f2bf(fmaf((float)((qv[8 + kk] >> shift) & 15u), sc, zo));
            *(short8*)b_wr       = bw0;
            *(short8*)(b_wr + 8) = bw1;

            __syncthreads();

            short8 af[4], bf[4];
            #pragma unroll
            for (int mt = 0; mt < 4; ++mt)
                af[mt] = *(const short8*)(a_rd + mt * 16 * LDA);
            #pragma unroll
            for (int nt = 0; nt < 4; ++nt)
                bf[nt] = *(const short8*)(b_rd + nt * 16 * LDB);

            #pragma unroll
            for (int mt = 0; mt < 4; ++mt)
                #pragma unroll
                for (int nt = 0; nt < 4; ++nt)
                    acc[mt][nt] = __builtin_amdgcn_mfma_f32_16x16x32_bf16(
                        af[mt], bf[nt], acc[mt][nt], 0, 0, 0);
        }
    }

    #pragma unroll
    for (int mt = 0; mt < 4; ++mt) {
        #pragma unroll
        for (int nt = 0; nt < 4; ++nt) {
            const int col = n0 + wn + nt * 16 + lrow;
            float* op = out + (size_t)(m0 + wm + mt * 16 + quad * 4) * OUT_F + col;
            #pragma unroll
            for (int r = 0; r < 4; ++r)
                op[(size_t)r * OUT_F] = acc[mt][nt][r];
        }
    }
}

extern "C" void kernel_launch(void* const* d_in, const int* in_sizes, int n_in,
                              void* d_out, int out_size, void* d_ws, size_t ws_size,
                              hipStream_t stream) {
    const float* input   = (const float*)d_in[0];
    const int*   qweight = (const int*)d_in[1];
    const int*   qzeros  = (const int*)d_in[2];
    const float* scales  = (const float*)d_in[3];
    float*       out     = (float*)d_out;

    const size_t WT_BYTES = (size_t)OUT_F * IN_F * 2;   // 90,177,536
    const size_t AB_BYTES = (size_t)M_TOT * IN_F * 2;   // 33,554,432

    if (ws_size >= WT_BYTES + AB_BYTES) {
        short* wt = (short*)d_ws;
        short* ab = (short*)((char*)d_ws + WT_BYTES);

        dequant_kernel<<<(QCOLS * 128) / 256, 256, 0, stream>>>(qweight, qzeros, scales, wt);
        cast_kernel<<<(size_t)M_TOT * IN_F / 8 / 256, 256, 0, stream>>>(input, ab);
        dim3 grid(OUT_F / 128, M_TOT / 128);   // (86, 32)
        gemm_kernel<<<grid, 256, 0, stream>>>(ab, wt, out);
    } else {
        dim3 grid(OUT_F / BN, M_TOT / BM);
        wql_kernel<<<grid, 256, 0, stream>>>(input, qweight, qzeros, scales, out);
    }
}

// Round 3
// 607.878 us; speedup vs baseline: 1.6437x; 1.1977x over previous
//
#include <hip/hip_runtime.h>
#include <stdint.h>

// Problem constants
#define IN_F   4096
#define OUT_F  11008
#define QCOLS  (OUT_F / 8)   // 1376
#define NGRP   32
#define M_TOT  4096

typedef __attribute__((ext_vector_type(8))) short short8;
typedef __attribute__((ext_vector_type(4))) float floatx4;

// fp32 -> bf16 round-to-nearest-even
__device__ __forceinline__ short f2bf(float f) {
    union { float f; uint32_t u; } v; v.f = f;
    uint32_t u = v.u;
    u += 0x7FFFu + ((u >> 16) & 1u);
    return (short)(u >> 16);
}

// ---------------------------------------------------------------------------
// Kernel 1: dequant qweight (4-bit, group=128) -> bf16 W^T[n][k] row-major.
// Block = 256-n x 64-k tile. qw tile staged via LDS (coalesced reads);
// thread owns one n-row -> 128 B contiguous writes per lane (wave = 8 KB linear).
// ---------------------------------------------------------------------------
__global__ __launch_bounds__(256)
void dequant_kernel(const int* __restrict__ qw, const int* __restrict__ qz,
                    const float* __restrict__ scl, short* __restrict__ wt)
{
    __shared__ int qlds[64 * 32];   // 8 KB: qw[k0:k0+64][c0:c0+32]

    const int tid = threadIdx.x;
    const int nb  = blockIdx.x;       // 0..42  (n-tile)
    const int kb  = blockIdx.y;       // 0..63  (k-tile)
    const int n0  = nb * 256;
    const int c0  = nb * 32;
    const int k0  = kb * 64;
    const int g   = kb >> 1;          // quant group (64k tile sits in one group)

    // ---- stage qw tile: 2048 ints, 8 per thread, coalesced
    #pragma unroll
    for (int i = 0; i < 8; ++i) {
        const int f = tid + i * 256;          // 0..2047
        const int k = f >> 5, c = f & 31;
        qlds[f] = qw[(size_t)(k0 + k) * QCOLS + c0 + c];
    }
    __syncthreads();

    // ---- per-thread invariants (one output row n0+tid)
    const int   cl = tid >> 3;
    const int   sh = (tid & 7) << 2;
    const uint32_t z  = (uint32_t)qz[(size_t)g * QCOLS + c0 + cl];
    const float sc = scl[(size_t)g * OUT_F + n0 + tid];
    const float zo = -(float)((z >> sh) & 15u) * sc;

    short8 o[8];
    #pragma unroll
    for (int i = 0; i < 8; ++i) {
        #pragma unroll
        for (int kk = 0; kk < 8; ++kk) {
            const uint32_t q = (uint32_t)qlds[(i * 8 + kk) * 32 + cl];
            o[i][kk] = f2bf(fmaf((float)((q >> sh) & 15u), sc, zo));
        }
    }

    short* dst = wt + (size_t)(n0 + tid) * IN_F + k0;
    #pragma unroll
    for (int i = 0; i < 8; ++i)
        *(short8*)(dst + i * 8) = o[i];
}

// ---------------------------------------------------------------------------
// Kernel 2: cast A fp32 -> bf16 (row-major [m][k]) in workspace
// ---------------------------------------------------------------------------
__global__ __launch_bounds__(256)
void cast_kernel(const float* __restrict__ A, short* __restrict__ Ab)
{
    const size_t i = ((size_t)blockIdx.x * 256 + threadIdx.x) * 8;
    const float4 a0 = *(const float4*)(A + i);
    const float4 a1 = *(const float4*)(A + i + 4);
    short8 o;
    o[0] = f2bf(a0.x); o[1] = f2bf(a0.y); o[2] = f2bf(a0.z); o[3] = f2bf(a0.w);
    o[4] = f2bf(a1.x); o[5] = f2bf(a1.y); o[6] = f2bf(a1.z); o[7] = f2bf(a1.w);
    *(short8*)(Ab + i) = o;
}

// ---------------------------------------------------------------------------
// Kernel 3: bf16 GEMM, m97-style. 128x128 tile, BK=64, global_load_lds w=16,
// XOR-swizzled LDS. Grid is m-fast so the concurrent block set shares a
// narrow Wt n-panel + all of A -> L3-resident working set.
// ---------------------------------------------------------------------------
#define GBK 64

__global__ __launch_bounds__(256, 3)
void gemm_kernel(const short* __restrict__ Ab, const short* __restrict__ Bt,
                 float* __restrict__ out)
{
    __shared__ short As[128 * GBK];   // 16 KB, unpadded (global_load_lds req.)
    __shared__ short Bs[128 * GBK];   // 16 KB

    const int tid  = threadIdx.x;
    const int lane = tid & 63;
    const int w    = tid >> 6;
    const int m0   = blockIdx.x * 128;   // m-fast dispatch
    const int n0   = blockIdx.y * 128;

    // ---- staging: wave w owns slots w*4..w*4+3; slot = 8 rows x 128 B.
    const int srow = lane >> 3;
    const int kseg = (lane & 7) ^ srow;          // XOR swizzle
    const short* agp[4];
    const short* bgp[4];
    short* alp[4];
    short* blp[4];
    #pragma unroll
    for (int s = 0; s < 4; ++s) {
        const int slot = w * 4 + s;
        const int row  = slot * 8 + srow;
        agp[s] = Ab + (size_t)(m0 + row) * IN_F + kseg * 8;
        bgp[s] = Bt + (size_t)(n0 + row) * IN_F + kseg * 8;
        alp[s] = As + slot * 512;   // HW appends lane*16B
        blp[s] = Bs + slot * 512;
    }

    // ---- MFMA fragment roles
    const int lrow = lane & 15;
    const int quad = lane >> 4;
    const int wm   = ((w >> 1) & 1) << 6;
    const int wn   = (w & 1) << 6;

    int aoff[4], boff[4];
    #pragma unroll
    for (int i = 0; i < 4; ++i) {
        const int swz = (quad ^ (lrow & 7)) * 8;
        aoff[i] = (wm + i * 16 + lrow) * GBK + swz;
        boff[i] = (wn + i * 16 + lrow) * GBK + swz;
    }

    floatx4 acc[4][4];
    #pragma unroll
    for (int i = 0; i < 4; ++i)
        #pragma unroll
        for (int j = 0; j < 4; ++j)
            acc[i][j] = (floatx4)0.f;

    for (int it = 0; it < IN_F / GBK; ++it) {
        __syncthreads();
        #pragma unroll
        for (int s = 0; s < 4; ++s) {
            __builtin_amdgcn_global_load_lds(
                (const __attribute__((address_space(1))) void*)agp[s],
                (__attribute__((address_space(3))) void*)alp[s], 16, 0, 0);
            __builtin_amdgcn_global_load_lds(
                (const __attribute__((address_space(1))) void*)bgp[s],
                (__attribute__((address_space(3))) void*)blp[s], 16, 0, 0);
            agp[s] += GBK;
            bgp[s] += GBK;
        }
        __syncthreads();

        #pragma unroll
        for (int kx = 0; kx < 64; kx += 32) {
            short8 af[4], bf[4];
            #pragma unroll
            for (int mt = 0; mt < 4; ++mt)
                af[mt] = *(const short8*)(As + (aoff[mt] ^ kx));
            #pragma unroll
            for (int nt = 0; nt < 4; ++nt)
                bf[nt] = *(const short8*)(Bs + (boff[nt] ^ kx));
            #pragma unroll
            for (int mt = 0; mt < 4; ++mt)
                #pragma unroll
                for (int nt = 0; nt < 4; ++nt)
                    acc[mt][nt] = __builtin_amdgcn_mfma_f32_16x16x32_bf16(
                        af[mt], bf[nt], acc[mt][nt], 0, 0, 0);
        }
    }

    // ---- epilogue: C/D layout col = lane&15, row = quad*4 + reg
    #pragma unroll
    for (int mt = 0; mt < 4; ++mt) {
        #pragma unroll
        for (int nt = 0; nt < 4; ++nt) {
            const int col = n0 + wn + nt * 16 + lrow;
            float* op = out + (size_t)(m0 + wm + mt * 16 + quad * 4) * OUT_F + col;
            #pragma unroll
            for (int r = 0; r < 4; ++r)
                op[(size_t)r * OUT_F] = acc[mt][nt][r];
        }
    }
}

// ---------------------------------------------------------------------------
// Fallback: round-1 fused kernel (used only if workspace is too small)
// ---------------------------------------------------------------------------
#define BM 128
#define BN 128
#define LDA 40
#define LDB 40

__global__ __launch_bounds__(256, 2)
void wql_kernel(const float* __restrict__ A,
                const int*   __restrict__ qw,
                const int*   __restrict__ qz,
                const float* __restrict__ scl,
                float*       __restrict__ out)
{
    __shared__ short As[BM * LDA];
    __shared__ short Bs[BN * LDB];

    const int tid = threadIdx.x;
    const int m0  = blockIdx.y * BM;
    const int n0  = blockIdx.x * BN;

    const int a_row  = tid >> 1;
    const int a_kseg = (tid & 1) << 4;
    const float* a_base = A + (size_t)(m0 + a_row) * IN_F + a_kseg;
    short* a_wr = &As[a_row * LDA + a_kseg];

    const int b_n     = tid & 127;
    const int b_khalf = (tid >> 7) << 4;
    const int c_glob  = (n0 >> 3) + (b_n >> 3);
    const int shift   = (b_n & 7) << 2;
    short* b_wr = &Bs[b_n * LDB + b_khalf];

    const int lane = tid & 63;
    const int wm   = ((tid >> 7) & 1) << 6;
    const int wn   = ((tid >> 6) & 1) << 6;
    const int lrow = lane & 15;
    const int quad = lane >> 4;

    const short* a_rd = &As[(wm + lrow) * LDA + quad * 8];
    const short* b_rd = &Bs[(wn + lrow) * LDB + quad * 8];

    floatx4 acc[4][4];
    #pragma unroll
    for (int i = 0; i < 4; ++i)
        #pragma unroll
        for (int j = 0; j < 4; ++j)
            acc[i][j] = (floatx4)0.f;

    for (int g = 0; g < NGRP; ++g) {
        const uint32_t z  = (uint32_t)qz[g * QCOLS + c_glob];
        const float    sc = scl[g * OUT_F + n0 + b_n];
        const float    zo = -(float)((z >> shift) & 15u) * sc;

        #pragma unroll 1
        for (int t4 = 0; t4 < 4; ++t4) {
            const int k0 = (g << 7) + (t4 << 5);
            const float4* ap = (const float4*)(a_base + k0);
            float4 av0 = ap[0], av1 = ap[1], av2 = ap[2], av3 = ap[3];

            const int* qp = qw + (size_t)(k0 + b_khalf) * QCOLS + c_glob;
            uint32_t qv[16];
            #pragma unroll
            for (int kk = 0; kk < 16; ++kk) qv[kk] = (uint32_t)qp[kk * QCOLS];

            __syncthreads();

            short8 aw0, aw1;
            aw0[0]=f2bf(av0.x); aw0[1]=f2bf(av0.y); aw0[2]=f2bf(av0.z); aw0[3]=f2bf(av0.w);
            aw0[4]=f2bf(av1.x); aw0[5]=f2bf(av1.y); aw0[6]=f2bf(av1.z); aw0[7]=f2bf(av1.w);
            aw1[0]=f2bf(av2.x); aw1[1]=f2bf(av2.y); aw1[2]=f2bf(av2.z); aw1[3]=f2bf(av2.w);
            aw1[4]=f2bf(av3.x); aw1[5]=f2bf(av3.y); aw1[6]=f2bf(av3.z); aw1[7]=f2bf(av3.w);
            *(short8*)a_wr       = aw0;
            *(short8*)(a_wr + 8) = aw1;

            short8 bw0, bw1;
            #pragma unroll
            for (int kk = 0; kk < 8; ++kk)
                bw0[kk] = f2bf(fmaf((float)((qv[kk] >> shift) & 15u), sc, zo));
            #pragma unroll
            for (int kk = 0; kk < 8; ++kk)
                bw1[kk] = f2bf(fmaf((float)((qv[8 + kk] >> shift) & 15u), sc, zo));
            *(short8*)b_wr       = bw0;
            *(short8*)(b_wr + 8) = bw1;

            __syncthreads();

            short8 af[4], bf[4];
            #pragma unroll
            for (int mt = 0; mt < 4; ++mt)
                af[mt] = *(const short8*)(a_rd + mt * 16 * LDA);
            #pragma unroll
            for (int nt = 0; nt < 4; ++nt)
                bf[nt] = *(const short8*)(b_rd + nt * 16 * LDB);

            #pragma unroll
            for (int mt = 0; mt < 4; ++mt)
                #pragma unroll
                for (int nt = 0; nt < 4; ++nt)
                    acc[mt][nt] = __builtin_amdgcn_mfma_f32_16x16x32_bf16(
                        af[mt], bf[nt], acc[mt][nt], 0, 0, 0);
        }
    }

    #pragma unroll
    for (int mt = 0; mt < 4; ++mt) {
        #pragma unroll
        for (int nt = 0; nt < 4; ++nt) {
            const int col = n0 + wn + nt * 16 + lrow;
            float* op = out + (size_t)(m0 + wm + mt * 16 + quad * 4) * OUT_F + col;
            #pragma unroll
            for (int r = 0; r < 4; ++r)
                op[(size_t)r * OUT_F] = acc[mt][nt][r];
        }
    }
}

extern "C" void kernel_launch(void* const* d_in, const int* in_sizes, int n_in,
                              void* d_out, int out_size, void* d_ws, size_t ws_size,
                              hipStream_t stream) {
    const float* input   = (const float*)d_in[0];
    const int*   qweight = (const int*)d_in[1];
    const int*   qzeros  = (const int*)d_in[2];
    const float* scales  = (const float*)d_in[3];
    float*       out     = (float*)d_out;

    const size_t WT_BYTES = (size_t)OUT_F * IN_F * 2;   // 90,177,536
    const size_t AB_BYTES = (size_t)M_TOT * IN_F * 2;   // 33,554,432

    if (ws_size >= WT_BYTES + AB_BYTES) {
        short* wt = (short*)d_ws;
        short* ab = (short*)((char*)d_ws + WT_BYTES);

        dim3 dq_grid(OUT_F / 256, IN_F / 64);   // (43, 64)
        dequant_kernel<<<dq_grid, 256, 0, stream>>>(qweight, qzeros, scales, wt);
        cast_kernel<<<(size_t)M_TOT * IN_F / 8 / 256, 256, 0, stream>>>(input, ab);
        dim3 grid(M_TOT / 128, OUT_F / 128);    // (32, 86), m-fast
        gemm_kernel<<<grid, 256, 0, stream>>>(ab, wt, out);
    } else {
        dim3 grid(OUT_F / BN, M_TOT / BM);
        wql_kernel<<<grid, 256, 0, stream>>>(input, qweight, qzeros, scales, out);
    }
}